// Round 5
// baseline (286.764 us; speedup 1.0000x reference)
//
#include <hip/hip_runtime.h>
#include <hip/hip_bf16.h>
#include <cstdint>
#include <math.h>

using bf16 = __hip_bfloat16;
typedef __attribute__((ext_vector_type(8))) short bf16x8;
typedef __attribute__((ext_vector_type(4))) float f32x4;
typedef __attribute__((ext_vector_type(16))) float f32x16;
typedef __attribute__((ext_vector_type(4))) uint32_t u32x4;

#define DEV __device__ __forceinline__

DEV float b2f(unsigned short u) { return __uint_as_float(((uint32_t)u) << 16); }
DEV float bfl(bf16 h) { return __bfloat162float(h); }
DEV short f2bs(float f) { bf16 h = __float2bfloat16(f); return *(short*)&h; }
// explicit bf16-pair pack: a in low 16 bits (lower address), b in high.
DEV uint32_t pk2(float a, float b) {
  return (uint32_t)(unsigned short)f2bs(a) |
         ((uint32_t)(unsigned short)f2bs(b) << 16);
}
DEV float ldv(const void* p, int isbf, int i) {
  return isbf ? bfl(((const bf16*)p)[i]) : ((const float*)p)[i];
}
// hardware packed f32->bf16 pair: low word = a, high word = b
DEV uint32_t cvtpk_bf16(float a, float b) {
  uint32_t r;
  asm("v_cvt_pk_bf16_f32 %0, %1, %2" : "=v"(r) : "v"(a), "v"(b));
  return r;
}

// weight fragment: 8 contiguous elems at w[row*K + off] -> bf16x8
DEV bf16x8 load_wfrag(const void* w, int isbf, int row, int K, int off) {
  bf16x8 r;
  if (isbf) {
    r = *(const bf16x8*)((const short*)w + (size_t)row * K + off);
  } else {
    const float* f = (const float*)w + (size_t)row * K + off;
    float4 a = *(const float4*)f, b = *(const float4*)(f + 4);
    r[0] = f2bs(a.x); r[1] = f2bs(a.y); r[2] = f2bs(a.z); r[3] = f2bs(a.w);
    r[4] = f2bs(b.x); r[5] = f2bs(b.y); r[6] = f2bs(b.z); r[7] = f2bs(b.w);
  }
  return r;
}

// ---------------------------------------------------------------------------
// dtype sniffer — EXACT round-3 version (validated).
// ---------------------------------------------------------------------------
__global__ __launch_bounds__(256) void sniff_kernel(
    const unsigned short* __restrict__ xr, int* __restrict__ flag)
{
  int tid = threadIdx.x;
  int good = 0;
  for (int k = tid; k < 16384; k += 256) {
    unsigned short u = xr[2 * k];
    int e = (u >> 7) & 0xFF;
    good += (e >= 0x6A && e <= 0x86) ? 1 : 0;
  }
  __shared__ int r[256];
  r[tid] = good;
  __syncthreads();
  for (int off = 128; off; off >>= 1) {
    if (tid < off) r[tid] += r[tid + off];
    __syncthreads();
  }
  if (tid == 0) *flag = (r[0] > 9830) ? 1 : 0;
}

// ---------------------------------------------------------------------------
// transpose x [b][c(256)][n(4096)] (flag dtype) -> xT [b][n][c] bf16.
// EXACT round-3 version (validated).
// ---------------------------------------------------------------------------
__global__ __launch_bounds__(256) void transpose_x(
    const void* __restrict__ x, short* __restrict__ xT, const int* __restrict__ flag)
{
  const int isbf = *flag;
  __shared__ short lt[64 * 71];
  const int n0 = blockIdx.x * 64, c0 = blockIdx.y * 64, b = blockIdx.z;
  const int tid = threadIdx.x;
  for (int it = 0; it < 4; ++it) {
    int idx4 = it * 256 + tid;
    int ci = idx4 >> 4, n4 = (idx4 & 15) * 4;
    size_t go = ((size_t)(b * 256 + c0 + ci)) * 4096 + n0 + n4;
    if (isbf) {
      ushort4 v = *(const ushort4*)((const unsigned short*)x + go);
      lt[ci * 71 + n4 + 0] = v.x; lt[ci * 71 + n4 + 1] = v.y;
      lt[ci * 71 + n4 + 2] = v.z; lt[ci * 71 + n4 + 3] = v.w;
    } else {
      float4 v = *(const float4*)((const float*)x + go);
      lt[ci * 71 + n4 + 0] = f2bs(v.x); lt[ci * 71 + n4 + 1] = f2bs(v.y);
      lt[ci * 71 + n4 + 2] = f2bs(v.z); lt[ci * 71 + n4 + 3] = f2bs(v.w);
    }
  }
  __syncthreads();
  for (int it = 0; it < 4; ++it) {
    int idx4 = it * 256 + tid;
    int n = idx4 >> 4, c4 = (idx4 & 15) * 4;
    ushort4 v;
    v.x = (unsigned short)lt[(c4 + 0) * 71 + n];
    v.y = (unsigned short)lt[(c4 + 1) * 71 + n];
    v.z = (unsigned short)lt[(c4 + 2) * 71 + n];
    v.w = (unsigned short)lt[(c4 + 3) * 71 + n];
    *(ushort4*)(xT + ((size_t)(b * 4096 + n0 + n)) * 256 + c0 + c4) = v;
  }
}

// ---------------------------------------------------------------------------
// conv_t: out[b][n][co=128] — EXACT round-3 version (validated).
// ---------------------------------------------------------------------------
__global__ __launch_bounds__(256) void conv_t_k(
    const short* __restrict__ xT, const void* __restrict__ w,
    const void* __restrict__ bias, short* __restrict__ out,
    const int* __restrict__ flag)
{
  const int isbf = *flag;
  __shared__ short sh[64 * 264];
  const int b = blockIdx.y, nbase = blockIdx.x * 64, tid = threadIdx.x;
  const int ln = tid & 15, q = (tid >> 4) & 3, wv = tid >> 6;
  for (int it = 0; it < 16; ++it) {
    int idx4 = it * 256 + tid;
    int n = idx4 >> 6, c4 = (idx4 & 63) * 4;
    *(ushort4*)&sh[n * 264 + c4] =
        *(const ushort4*)(xT + ((size_t)(b * 4096 + nbase + n)) * 256 + c4);
  }
  __syncthreads();
  f32x4 zero = {0.f, 0.f, 0.f, 0.f};
  f32x4 acc[4][2];
  for (int nt = 0; nt < 4; ++nt) for (int ti = 0; ti < 2; ++ti) acc[nt][ti] = zero;

  for (int kk = 0; kk < 8; ++kk) {
    int off = kk * 32 + q * 8;
    bf16x8 a[4];
    #pragma unroll
    for (int nt = 0; nt < 4; ++nt)
      a[nt] = *(const bf16x8*)&sh[(16 * nt + ln) * 264 + off];
    #pragma unroll
    for (int ti = 0; ti < 2; ++ti) {
      bf16x8 bw = load_wfrag(w, isbf, 16 * (2 * wv + ti) + ln, 256, off);
      #pragma unroll
      for (int nt = 0; nt < 4; ++nt)
        acc[nt][ti] = __builtin_amdgcn_mfma_f32_16x16x32_bf16(a[nt], bw, acc[nt][ti], 0, 0, 0);
    }
  }
  __syncthreads();
  float bv[2];
  for (int ti = 0; ti < 2; ++ti) bv[ti] = ldv(bias, isbf, 16 * (2 * wv + ti) + ln);
  for (int nt = 0; nt < 4; ++nt)
    for (int ti = 0; ti < 2; ++ti)
      for (int r = 0; r < 4; ++r)
        sh[(16 * nt + q * 4 + r) * 136 + 16 * (2 * wv + ti) + ln] =
            f2bs(acc[nt][ti][r] + bv[ti]);
  __syncthreads();
  for (int it = 0; it < 8; ++it) {
    int idx4 = it * 256 + tid;
    int n = idx4 >> 5, c4 = (idx4 & 31) * 4;
    *(ushort4*)(out + ((size_t)(b * 4096 + nbase + n)) * 128 + c4) =
        *(const ushort4*)&sh[n * 136 + c4];
  }
}

// ---------------------------------------------------------------------------
// conv_n: out[b][CO][n] — EXACT round-3 version (validated).
// ---------------------------------------------------------------------------
template<int CO, int K>
__global__ __launch_bounds__(256) void conv_n_k(
    const short* __restrict__ inp, const void* __restrict__ w,
    const void* __restrict__ bias, short* __restrict__ out,
    const int* __restrict__ flag)
{
  const int isbf = *flag;
  constexpr int XS = 64 * (K + 8);
  constexpr int OS = CO * 68;
  __shared__ short sh[(XS > OS ? XS : OS)];
  const int b = blockIdx.y, nbase = blockIdx.x * 64, tid = threadIdx.x;
  const int ln = tid & 15, q = (tid >> 4) & 3, wv = tid >> 6;
  constexpr int TPW = CO / 64;
  constexpr int KS = (K == 256) ? 6 : 5;
  for (int it = 0; it < 64 * K / 1024; ++it) {
    int idx4 = it * 256 + tid;
    int n = idx4 >> KS, c4 = (idx4 & ((K / 4) - 1)) * 4;
    *(ushort4*)&sh[n * (K + 8) + c4] =
        *(const ushort4*)(inp + ((size_t)(b * 4096 + nbase + n)) * K + c4);
  }
  __syncthreads();
  f32x4 zero = {0.f, 0.f, 0.f, 0.f};
  f32x4 acc[TPW][4];
  for (int ti = 0; ti < TPW; ++ti) for (int nt = 0; nt < 4; ++nt) acc[ti][nt] = zero;

  for (int kk = 0; kk < K / 32; ++kk) {
    int off = kk * 32 + q * 8;
    bf16x8 bx[4];
    #pragma unroll
    for (int nt = 0; nt < 4; ++nt)
      bx[nt] = *(const bf16x8*)&sh[(16 * nt + ln) * (K + 8) + off];
    #pragma unroll
    for (int ti = 0; ti < TPW; ++ti) {
      bf16x8 aw = load_wfrag(w, isbf, 16 * (TPW * wv + ti) + ln, K, off);
      #pragma unroll
      for (int nt = 0; nt < 4; ++nt)
        acc[ti][nt] = __builtin_amdgcn_mfma_f32_16x16x32_bf16(aw, bx[nt], acc[ti][nt], 0, 0, 0);
    }
  }
  __syncthreads();
  for (int ti = 0; ti < TPW; ++ti)
    for (int r = 0; r < 4; ++r) {
      int co = 16 * (TPW * wv + ti) + q * 4 + r;
      float bb = ldv(bias, isbf, co);
      for (int nt = 0; nt < 4; ++nt)
        sh[co * 68 + 16 * nt + ln] = f2bs(acc[ti][nt][r] + bb);
    }
  __syncthreads();
  for (int it = 0; it < 64 * CO / 1024; ++it) {
    int idx4 = it * 256 + tid;
    int co = idx4 >> 4, n4 = (idx4 & 15) * 4;
    *(ushort4*)(out + ((size_t)(b * CO + co)) * 4096 + nbase + n4) =
        *(const ushort4*)&sh[co * 68 + n4];
  }
}

// ---------------------------------------------------------------------------
// pools — EXACT round-3 versions (validated).
// ---------------------------------------------------------------------------
__global__ __launch_bounds__(256) void pool_phi_kernel(
    const short* __restrict__ pc, short* __restrict__ phi)
{
  int idx = blockIdx.x * 256 + threadIdx.x;  // b*1024*128
  int ci = idx & 127, m = (idx >> 7) & 1023, b = idx >> 17;
  int mh = m >> 5, mw = m & 31;
  const short* p = pc + ((size_t)(b * 4096 + (mh * 2) * 64 + mw * 2)) * 128 + ci;
  float v = fmaxf(fmaxf(b2f(p[0]), b2f(p[128])),
                  fmaxf(b2f(p[64 * 128]), b2f(p[65 * 128])));
  phi[idx] = f2bs(v);
}

__global__ __launch_bounds__(256) void pool_g_kernel(
    const short* __restrict__ gc, short* __restrict__ g)
{
  int idx = blockIdx.x * 256 + threadIdx.x;  // (b*128+ci)*1024 + m
  int m = idx & 1023, bc = idx >> 10;
  int mh = m >> 5, mw = m & 31;
  const short* p = gc + (size_t)bc * 4096 + mh * 128 + mw * 2;
  float v = fmaxf(fmaxf(b2f(p[0]), b2f(p[1])), fmaxf(b2f(p[64]), b2f(p[65])));
  g[idx] = f2bs(v);
}

// ---------------------------------------------------------------------------
// MFMA flash attention — ROUND-11: round-10 + the LAST scratch elimination.
// Round-10 counters: VGPR still 108, WRITE_SIZE still 105 MB (y needs 8.4) —
// the `*(bf16x8*)&cc[i]` type-pun took the address of cc[] and pinned it to
// scratch (~32B/thread/iter round-trip). Fix: named scalars + bit_cast
// (register-to-register, no address taken anywhere).
// ---------------------------------------------------------------------------
__global__ __launch_bounds__(256, 2) void attn_kernel(
    const short* __restrict__ theta, const short* __restrict__ phi,
    const short* __restrict__ g, short* __restrict__ y)
{
  __shared__ alignas(16) char smem[51712];
  char* phs = smem;                        // [64 rows][256B]  phi tile (swz)
  char* gls = smem + 16384;                // [128 rows][128B] g tile (swz)
  float* comb = (float*)smem;              // [2*128][33] epilogue y-partials
  float* lred = (float*)(smem + 33792);    // [2][64] l partials
  short* yout = (short*)(smem + 34304);    // [64][136] final bf16 y tile

  const int b = blockIdx.y, nbase = blockIdx.x * 64, tid = threadIdx.x;
  const int l = tid & 63, wv = tid >> 6;
  const int ln32 = l & 31, h = l >> 5;
  const int nh = wv & 1, mh = wv >> 1;

  const short* phb = phi + (size_t)b * 1024 * 128;   // [m][128c]
  const short* gb  = g   + (size_t)b * 128 * 1024;   // [c][1024m]

  // loop-invariant theta B-fragments: B[k=c][col=n], n = nh*32 + ln32
  bf16x8 bth[8];
  {
    const short* tb = theta +
        ((size_t)(b * 4096 + nbase + nh * 32 + ln32)) * 128 + h * 8;
    #pragma unroll
    for (int kk = 0; kk < 8; ++kk)
      bth[kk] = *(const bf16x8*)(tb + kk * 16);
  }

  // prefetch tile 0 (ph: 1024 chunks = 64r x 16slots; gl: 128r x 8slots)
  uint4 pf_p[4], pf_g[4];
  #pragma unroll
  for (int it = 0; it < 4; ++it) {
    int ch = it * 256 + tid;
    int row = ch >> 4, sl = ch & 15;
    pf_p[it] = *(const uint4*)(phb + ((size_t)row) * 128 + sl * 8);
    int cr = ch >> 3, sg = ch & 7;
    pf_g[it] = *(const uint4*)(gb + (size_t)cr * 1024 + sg * 8);
  }

  f32x16 yacc0, yacc1, yacc2, yacc3;
  #pragma unroll
  for (int r = 0; r < 16; ++r) { yacc0[r] = 0.f; yacc1[r] = 0.f; yacc2[r] = 0.f; yacc3[r] = 0.f; }
  float lsum = 0.f;

  for (int mc = 0; mc < 16; ++mc) {
    // commit prefetched tile to LDS (swizzled)
    #pragma unroll
    for (int it = 0; it < 4; ++it) {
      int ch = it * 256 + tid;
      int row = ch >> 4, sl = ch & 15;
      *(uint4*)(phs + row * 256 + ((sl * 16) ^ ((row & 15) << 4))) = pf_p[it];
    }
    #pragma unroll
    for (int it = 0; it < 4; ++it) {
      int ch = it * 256 + tid;
      int cr = ch >> 3, sg = ch & 7;
      *(uint4*)(gls + cr * 128 + ((sg * 16) ^ ((cr & 7) << 4))) = pf_g[it];
    }
    __syncthreads();
    if (mc < 15) {
      int nm = mc + 1;
      #pragma unroll
      for (int it = 0; it < 4; ++it) {
        int ch = it * 256 + tid;
        int row = ch >> 4, sl = ch & 15;
        pf_p[it] = *(const uint4*)(phb + ((size_t)(nm * 64 + row)) * 128 + sl * 8);
        int cr = ch >> 3, sg = ch & 7;
        pf_g[it] = *(const uint4*)(gb + (size_t)cr * 1024 + nm * 64 + sg * 8);
      }
    }

    // QK^T: S^T(32m x 32n) for this wave's m-half
    const int mrow = mh * 32 + ln32;
    const char* pbase = phs + mrow * 256;
    const int mxor = (mrow & 15) << 4;
    f32x16 sA, sB;
    #pragma unroll
    for (int r = 0; r < 16; ++r) { sA[r] = 0.f; sB[r] = 0.f; }
    #pragma unroll
    for (int kk = 0; kk < 8; kk += 2) {
      bf16x8 a0 = *(const bf16x8*)(pbase + ((kk * 32 + h * 16) ^ mxor));
      bf16x8 a1 = *(const bf16x8*)(pbase + (((kk + 1) * 32 + h * 16) ^ mxor));
      sA = __builtin_amdgcn_mfma_f32_32x32x16_bf16(a0, bth[kk], sA, 0, 0, 0);
      sB = __builtin_amdgcn_mfma_f32_32x32x16_bf16(a1, bth[kk + 1], sB, 0, 0, 0);
    }
    // softmax numerator in-register; lane holds P[n=ln32][m-pattern]
    float p[16];
    #pragma unroll
    for (int r = 0; r < 16; ++r) {
      p[r] = __expf(fminf(sA[r] + sB[r], 80.f));
      lsum += p[r];
    }
    // P -> bf16 PV A-fragments (k = m): cvt_pk pairs + half-lane swaps.
    // Named scalars + bit_cast: NO address taken, stays in registers.
    uint32_t cc0 = cvtpk_bf16(p[0], p[1]);
    uint32_t cc1 = cvtpk_bf16(p[2], p[3]);
    uint32_t cc2 = cvtpk_bf16(p[4], p[5]);
    uint32_t cc3 = cvtpk_bf16(p[6], p[7]);
    uint32_t cc4 = cvtpk_bf16(p[8], p[9]);
    uint32_t cc5 = cvtpk_bf16(p[10], p[11]);
    uint32_t cc6 = cvtpk_bf16(p[12], p[13]);
    uint32_t cc7 = cvtpk_bf16(p[14], p[15]);
    asm volatile("v_permlane32_swap_b32 %0, %1" : "+v"(cc0), "+v"(cc2));
    asm volatile("v_permlane32_swap_b32 %0, %1" : "+v"(cc1), "+v"(cc3));
    asm volatile("v_permlane32_swap_b32 %0, %1" : "+v"(cc4), "+v"(cc6));
    asm volatile("v_permlane32_swap_b32 %0, %1" : "+v"(cc5), "+v"(cc7));
    u32x4 wa0 = {cc0, cc1, cc2, cc3};
    u32x4 wa1 = {cc4, cc5, cc6, cc7};
    bf16x8 pa0 = __builtin_bit_cast(bf16x8, wa0);  // m = mh*32 + 0..15
    bf16x8 pa1 = __builtin_bit_cast(bf16x8, wa1);  // m = mh*32 + 16..31

    // PV: yacc[ct] += P(32n x 32m) * g(32m x 32c)  (compile-time indices)
    const int gxor = (ln32 & 7) << 4;
    {
      const char* gbase = gls + (0 * 32 + ln32) * 128;
      bf16x8 g0 = *(const bf16x8*)(gbase + ((mh * 64 + h * 16) ^ gxor));
      bf16x8 g1 = *(const bf16x8*)(gbase + ((mh * 64 + 32 + h * 16) ^ gxor));
      yacc0 = __builtin_amdgcn_mfma_f32_32x32x16_bf16(pa0, g0, yacc0, 0, 0, 0);
      yacc0 = __builtin_amdgcn_mfma_f32_32x32x16_bf16(pa1, g1, yacc0, 0, 0, 0);
    }
    {
      const char* gbase = gls + (1 * 32 + ln32) * 128;
      bf16x8 g0 = *(const bf16x8*)(gbase + ((mh * 64 + h * 16) ^ gxor));
      bf16x8 g1 = *(const bf16x8*)(gbase + ((mh * 64 + 32 + h * 16) ^ gxor));
      yacc1 = __builtin_amdgcn_mfma_f32_32x32x16_bf16(pa0, g0, yacc1, 0, 0, 0);
      yacc1 = __builtin_amdgcn_mfma_f32_32x32x16_bf16(pa1, g1, yacc1, 0, 0, 0);
    }
    {
      const char* gbase = gls + (2 * 32 + ln32) * 128;
      bf16x8 g0 = *(const bf16x8*)(gbase + ((mh * 64 + h * 16) ^ gxor));
      bf16x8 g1 = *(const bf16x8*)(gbase + ((mh * 64 + 32 + h * 16) ^ gxor));
      yacc2 = __builtin_amdgcn_mfma_f32_32x32x16_bf16(pa0, g0, yacc2, 0, 0, 0);
      yacc2 = __builtin_amdgcn_mfma_f32_32x32x16_bf16(pa1, g1, yacc2, 0, 0, 0);
    }
    {
      const char* gbase = gls + (3 * 32 + ln32) * 128;
      bf16x8 g0 = *(const bf16x8*)(gbase + ((mh * 64 + h * 16) ^ gxor));
      bf16x8 g1 = *(const bf16x8*)(gbase + ((mh * 64 + 32 + h * 16) ^ gxor));
      yacc3 = __builtin_amdgcn_mfma_f32_32x32x16_bf16(pa0, g0, yacc3, 0, 0, 0);
      yacc3 = __builtin_amdgcn_mfma_f32_32x32x16_bf16(pa1, g1, yacc3, 0, 0, 0);
    }
    __syncthreads();
  }

  // ---- epilogue: combine m-halves, normalize, store ----
  float lf = lsum + __shfl_xor(lsum, 32);   // full l over this wave's m-half

  // phase B: write the OTHER mh-half's ct-pair + l partials.
  #define COMB_STORE(CT, YV)                                         \
    {                                                                \
      _Pragma("unroll")                                              \
      for (int r = 0; r < 16; ++r) {                                 \
        int n = (r & 3) + 8 * (r >> 2) + 4 * h;                      \
        comb[((nh * 4 + (CT)) * 32 + ln32) * 33 + n] = (YV)[r];      \
      }                                                              \
    }
  if (mh == 0) { COMB_STORE(2, yacc2); COMB_STORE(3, yacc3); }
  else         { COMB_STORE(0, yacc0); COMB_STORE(1, yacc1); }
  if (l < 32) lred[mh * 64 + nh * 32 + l] = lf;
  __syncthreads();

  // phase D: finalize own ct-pair (own partial + partner's), normalize
  float linv[16];
  #pragma unroll
  for (int r = 0; r < 16; ++r) {
    int n = (r & 3) + 8 * (r >> 2) + 4 * h;
    linv[r] = 1.0f / (lred[nh * 32 + n] + lred[64 + nh * 32 + n]);
  }
  #define FINAL_STORE(CT, YV)                                              \
    {                                                                      \
      _Pragma("unroll")                                                    \
      for (int r = 0; r < 16; ++r) {                                       \
        int n = (r & 3) + 8 * (r >> 2) + 4 * h;                            \
        float v = (YV)[r] + comb[((nh * 4 + (CT)) * 32 + ln32) * 33 + n];  \
        yout[(nh * 32 + n) * 136 + (CT) * 32 + ln32] = f2bs(v * linv[r]);  \
      }                                                                    \
    }
  if (mh == 0) { FINAL_STORE(0, yacc0); FINAL_STORE(1, yacc1); }
  else         { FINAL_STORE(2, yacc2); FINAL_STORE(3, yacc3); }
  #undef COMB_STORE
  #undef FINAL_STORE
  __syncthreads();
  for (int it = 0; it < 8; ++it) {
    int idx4 = it * 256 + tid;
    int n = idx4 >> 5, c4 = (idx4 & 31) * 4;
    *(ushort4*)(y + ((size_t)(b * 4096 + nbase + n)) * 128 + c4) =
        *(const ushort4*)&yout[n * 136 + c4];
  }
}

// ---------------------------------------------------------------------------
// conv_W + BN partial-stat atomics — EXACT round-4 version (validated).
// ---------------------------------------------------------------------------
__global__ __launch_bounds__(256, 4) void convW_k(
    const short* __restrict__ yb, const void* __restrict__ w,
    const void* __restrict__ bias, short* __restrict__ Wy,
    float* __restrict__ stats, const int* __restrict__ flag)
{
  const int isbf = *flag;
  __shared__ short sh[256 * 72];
  const int b = blockIdx.y, nbase = blockIdx.x * 64, tid = threadIdx.x;
  const int ln = tid & 15, q = (tid >> 4) & 3, wv = tid >> 6;

  for (int it = 0; it < 4; ++it) {
    int idx8 = it * 256 + tid;
    int n = idx8 >> 4, c8 = (idx8 & 15) * 8;
    *(uint4*)&sh[n * 136 + c8] =
        *(const uint4*)(yb + ((size_t)(b * 4096 + nbase + n)) * 128 + c8);
  }
  __syncthreads();
  f32x4 zero = {0.f, 0.f, 0.f, 0.f};
  f32x4 acc[4][4];
  for (int ti = 0; ti < 4; ++ti)
    for (int nt = 0; nt < 4; ++nt) acc[ti][nt] = zero;

  for (int kk = 0; kk < 4; ++kk) {
    int off = kk * 32 + q * 8;
    bf16x8 bx[4];
    #pragma unroll
    for (int nt = 0; nt < 4; ++nt)
      bx[nt] = *(const bf16x8*)&sh[(16 * nt + ln) * 136 + off];
    #pragma unroll
    for (int ti = 0; ti < 4; ++ti) {
      bf16x8 aw = load_wfrag(w, isbf, 16 * (4 * wv + ti) + ln, 128, off);
      #pragma unroll
      for (int nt = 0; nt < 4; ++nt)
        acc[ti][nt] = __builtin_amdgcn_mfma_f32_16x16x32_bf16(aw, bx[nt], acc[ti][nt], 0, 0, 0);
    }
  }
  __syncthreads();
  #pragma unroll
  for (int ti = 0; ti < 4; ++ti)
    #pragma unroll
    for (int r = 0; r < 4; ++r) {
      int co = 16 * (4 * wv + ti) + 4 * q + r;
      float bb = ldv(bias, isbf, co);
      #pragma unroll
      for (int nt = 0; nt < 4; ++nt)
        sh[co * 72 + 16 * nt + ln] = f2bs(acc[ti][nt][r] + bb);
    }
  __syncthreads();
  {
    int co = tid;
    float s = 0.f, s2 = 0.f;
    for (int i = 0; i < 64; ++i) {
      float v = b2f((unsigned short)sh[co * 72 + i]);
      s += v; s2 += v * v;
    }
    atomicAdd(&stats[co], s);
    atomicAdd(&stats[256 + co], s2);
  }
  for (int it = 0; it < 8; ++it) {
    int idx8 = it * 256 + tid;
    int co = idx8 >> 3, n8 = (idx8 & 7) * 8;
    *(uint4*)(Wy + ((size_t)(b * 256 + co)) * 4096 + nbase + n8) =
        *(const uint4*)&sh[co * 72 + n8];
  }
}

// ---------------------------------------------------------------------------
// BN apply + residual, x4 — EXACT round-4/6 version (validated).
// ---------------------------------------------------------------------------
__global__ __launch_bounds__(256) void bn_apply4(
    const short* __restrict__ Wy, const void* __restrict__ x,
    const float* __restrict__ stats, const void* __restrict__ gamma,
    const void* __restrict__ beta, void* __restrict__ out,
    const int* __restrict__ flag)
{
  const int isbf = *flag;
  int t = blockIdx.x * 256 + threadIdx.x;
  int idx4 = t * 4;
  int c = (idx4 >> 12) & 255;
  float s = stats[c], s2 = stats[256 + c];
  float mean = s * (1.0f / 32768.0f);
  float var = fmaxf(s2 * (1.0f / 32768.0f) - mean * mean, 0.f);
  float scale = rsqrtf(var + 1e-5f) * ldv(gamma, isbf, c);
  float shift = ldv(beta, isbf, c) - mean * scale;
  ushort4 wy = *(const ushort4*)(Wy + idx4);
  float xv[4];
  if (isbf) {
    ushort4 xu = *(const ushort4*)((const unsigned short*)x + idx4);
    xv[0] = b2f(xu.x); xv[1] = b2f(xu.y); xv[2] = b2f(xu.z); xv[3] = b2f(xu.w);
  } else {
    float4 xf = *(const float4*)((const float*)x + idx4);
    xv[0] = xf.x; xv[1] = xf.y; xv[2] = xf.z; xv[3] = xf.w;
  }
  float v0 = b2f(wy.x) * scale + shift + xv[0];
  float v1 = b2f(wy.y) * scale + shift + xv[1];
  float v2 = b2f(wy.z) * scale + shift + xv[2];
  float v3 = b2f(wy.w) * scale + shift + xv[3];
  if (isbf) {
    uint2 o; o.x = pk2(v0, v1); o.y = pk2(v2, v3);
    *(uint2*)((unsigned short*)out + idx4) = o;
  } else {
    float4 o = make_float4(v0, v1, v2, v3);
    *(float4*)((float*)out + idx4) = o;
  }
}

// ---------------------------------------------------------------------------
extern "C" void kernel_launch(void* const* d_in, const int* in_sizes, int n_in,
                              void* d_out, int out_size, void* d_ws, size_t ws_size,
                              hipStream_t stream) {
  const void* x       = d_in[0];
  const void* theta_w = d_in[1];
  const void* theta_b = d_in[2];
  const void* phi_w   = d_in[3];
  const void* phi_b   = d_in[4];
  const void* g_w     = d_in[5];
  const void* g_b     = d_in[6];
  const void* W_w     = d_in[7];
  const void* W_b     = d_in[8];
  const void* gamma   = d_in[9];
  const void* beta    = d_in[10];

  char* wsb = (char*)d_ws;
  // round-3 layout exactly:
  //   [0, 16.78M)      xT -> ybuf
  //   [16.78M, 25.17M) theta -> W_y first half
  //   [25.17M, 33.55M) scratch (phi_c then g_c) -> W_y second half
  //   [33.55M, 35.65M) phi   [b][m][ci]
  //   [35.65M, 37.75M) gg    [b][ci][m]
  //   [37.75M+)        stats (512 f32), flag
  short* xT      = (short*)(wsb + 0);
  short* ybuf    = (short*)(wsb + 0);
  short* theta   = (short*)(wsb + 16777216);
  short* W_y     = (short*)(wsb + 16777216);
  short* scratch = (short*)(wsb + 25165824);
  short* phi     = (short*)(wsb + 33554432);
  short* gg      = (short*)(wsb + 35651584);
  float* stats   = (float*)(wsb + 37748736);
  int*   flag    = (int*)  (wsb + 37750784);

  dim3 blk(256);
  dim3 cgrid(64, 8);
  dim3 tgrid(64, 4, 8);

  hipMemsetAsync(stats, 0, 2048, stream);
  sniff_kernel<<<1, blk, 0, stream>>>((const unsigned short*)x, flag);
  transpose_x<<<tgrid, blk, 0, stream>>>(x, xT, flag);
  conv_t_k<<<cgrid, blk, 0, stream>>>(xT, theta_w, theta_b, theta, flag);
  conv_t_k<<<cgrid, blk, 0, stream>>>(xT, phi_w, phi_b, scratch, flag);
  pool_phi_kernel<<<4096, blk, 0, stream>>>(scratch, phi);
  conv_n_k<128, 256><<<cgrid, blk, 0, stream>>>(xT, g_w, g_b, scratch, flag);
  pool_g_kernel<<<4096, blk, 0, stream>>>(scratch, gg);
  attn_kernel<<<cgrid, blk, 0, stream>>>(theta, phi, gg, ybuf);
  convW_k<<<cgrid, blk, 0, stream>>>(ybuf, W_w, W_b, W_y, stats, flag);
  bn_apply4<<<8192, blk, 0, stream>>>(W_y, x, stats, gamma, beta, d_out, flag);
}

// Round 6
// 244.590 us; speedup vs baseline: 1.1724x; 1.1724x over previous
//
#include <hip/hip_runtime.h>
#include <hip/hip_bf16.h>
#include <cstdint>
#include <math.h>

using bf16 = __hip_bfloat16;
typedef __attribute__((ext_vector_type(8))) short bf16x8;
typedef __attribute__((ext_vector_type(4))) float f32x4;

#define DEV __device__ __forceinline__

DEV float b2f(unsigned short u) { return __uint_as_float(((uint32_t)u) << 16); }
DEV float bfl(bf16 h) { return __bfloat162float(h); }
DEV short f2bs(float f) { bf16 h = __float2bfloat16(f); return *(short*)&h; }
// explicit bf16-pair pack: a in low 16 bits (lower address), b in high.
DEV uint32_t pk2(float a, float b) {
  return (uint32_t)(unsigned short)f2bs(a) |
         ((uint32_t)(unsigned short)f2bs(b) << 16);
}
DEV float ldv(const void* p, int isbf, int i) {
  return isbf ? bfl(((const bf16*)p)[i]) : ((const float*)p)[i];
}

// weight fragment: 8 contiguous elems at w[row*K + off] -> bf16x8
DEV bf16x8 load_wfrag(const void* w, int isbf, int row, int K, int off) {
  bf16x8 r;
  if (isbf) {
    r = *(const bf16x8*)((const short*)w + (size_t)row * K + off);
  } else {
    const float* f = (const float*)w + (size_t)row * K + off;
    float4 a = *(const float4*)f, b = *(const float4*)(f + 4);
    r[0] = f2bs(a.x); r[1] = f2bs(a.y); r[2] = f2bs(a.z); r[3] = f2bs(a.w);
    r[4] = f2bs(b.x); r[5] = f2bs(b.y); r[6] = f2bs(b.z); r[7] = f2bs(b.w);
  }
  return r;
}

// ---------------------------------------------------------------------------
// dtype sniffer — EXACT round-3 version (validated).
// ---------------------------------------------------------------------------
__global__ __launch_bounds__(256) void sniff_kernel(
    const unsigned short* __restrict__ xr, int* __restrict__ flag)
{
  int tid = threadIdx.x;
  int good = 0;
  for (int k = tid; k < 16384; k += 256) {
    unsigned short u = xr[2 * k];
    int e = (u >> 7) & 0xFF;
    good += (e >= 0x6A && e <= 0x86) ? 1 : 0;
  }
  __shared__ int r[256];
  r[tid] = good;
  __syncthreads();
  for (int off = 128; off; off >>= 1) {
    if (tid < off) r[tid] += r[tid + off];
    __syncthreads();
  }
  if (tid == 0) *flag = (r[0] > 9830) ? 1 : 0;
}

// ---------------------------------------------------------------------------
// transpose x [b][c(256)][n(4096)] (flag dtype) -> xT [b][n][c] bf16.
// EXACT round-3 version (validated).
// ---------------------------------------------------------------------------
__global__ __launch_bounds__(256) void transpose_x(
    const void* __restrict__ x, short* __restrict__ xT, const int* __restrict__ flag)
{
  const int isbf = *flag;
  __shared__ short lt[64 * 71];
  const int n0 = blockIdx.x * 64, c0 = blockIdx.y * 64, b = blockIdx.z;
  const int tid = threadIdx.x;
  for (int it = 0; it < 4; ++it) {
    int idx4 = it * 256 + tid;
    int ci = idx4 >> 4, n4 = (idx4 & 15) * 4;
    size_t go = ((size_t)(b * 256 + c0 + ci)) * 4096 + n0 + n4;
    if (isbf) {
      ushort4 v = *(const ushort4*)((const unsigned short*)x + go);
      lt[ci * 71 + n4 + 0] = v.x; lt[ci * 71 + n4 + 1] = v.y;
      lt[ci * 71 + n4 + 2] = v.z; lt[ci * 71 + n4 + 3] = v.w;
    } else {
      float4 v = *(const float4*)((const float*)x + go);
      lt[ci * 71 + n4 + 0] = f2bs(v.x); lt[ci * 71 + n4 + 1] = f2bs(v.y);
      lt[ci * 71 + n4 + 2] = f2bs(v.z); lt[ci * 71 + n4 + 3] = f2bs(v.w);
    }
  }
  __syncthreads();
  for (int it = 0; it < 4; ++it) {
    int idx4 = it * 256 + tid;
    int n = idx4 >> 4, c4 = (idx4 & 15) * 4;
    ushort4 v;
    v.x = (unsigned short)lt[(c4 + 0) * 71 + n];
    v.y = (unsigned short)lt[(c4 + 1) * 71 + n];
    v.z = (unsigned short)lt[(c4 + 2) * 71 + n];
    v.w = (unsigned short)lt[(c4 + 3) * 71 + n];
    *(ushort4*)(xT + ((size_t)(b * 4096 + n0 + n)) * 256 + c0 + c4) = v;
  }
}

// ---------------------------------------------------------------------------
// conv_tp: FUSED theta+phi 1x1 convs — ROUND-12 (under test).
// Both convs read the SAME xT tile; stage it once (shA persists), load each
// x-fragment a[nt] once, accumulate against both weight sets, then run the
// validated conv_t epilogue twice through a separate repack region shB.
// Saves one full 16.8 MB xT pass + half the staging writes + one launch.
// ---------------------------------------------------------------------------
__global__ __launch_bounds__(256) void conv_tp_k(
    const short* __restrict__ xT,
    const void* __restrict__ w1, const void* __restrict__ b1, short* __restrict__ out1,
    const void* __restrict__ w2, const void* __restrict__ b2, short* __restrict__ out2,
    const int* __restrict__ flag)
{
  const int isbf = *flag;
  __shared__ short shA[64 * 264];   // staging (persists through both epilogues)
  __shared__ short shB[64 * 136];   // repack region (used twice)
  const int b = blockIdx.y, nbase = blockIdx.x * 64, tid = threadIdx.x;
  const int ln = tid & 15, q = (tid >> 4) & 3, wv = tid >> 6;
  for (int it = 0; it < 16; ++it) {
    int idx4 = it * 256 + tid;
    int n = idx4 >> 6, c4 = (idx4 & 63) * 4;
    *(ushort4*)&shA[n * 264 + c4] =
        *(const ushort4*)(xT + ((size_t)(b * 4096 + nbase + n)) * 256 + c4);
  }
  __syncthreads();
  f32x4 zero = {0.f, 0.f, 0.f, 0.f};
  f32x4 acc1[4][2], acc2[4][2];
  for (int nt = 0; nt < 4; ++nt)
    for (int ti = 0; ti < 2; ++ti) { acc1[nt][ti] = zero; acc2[nt][ti] = zero; }

  for (int kk = 0; kk < 8; ++kk) {
    int off = kk * 32 + q * 8;
    bf16x8 a[4];
    #pragma unroll
    for (int nt = 0; nt < 4; ++nt)
      a[nt] = *(const bf16x8*)&shA[(16 * nt + ln) * 264 + off];
    #pragma unroll
    for (int ti = 0; ti < 2; ++ti) {
      bf16x8 bw1 = load_wfrag(w1, isbf, 16 * (2 * wv + ti) + ln, 256, off);
      #pragma unroll
      for (int nt = 0; nt < 4; ++nt)
        acc1[nt][ti] = __builtin_amdgcn_mfma_f32_16x16x32_bf16(a[nt], bw1, acc1[nt][ti], 0, 0, 0);
    }
    #pragma unroll
    for (int ti = 0; ti < 2; ++ti) {
      bf16x8 bw2 = load_wfrag(w2, isbf, 16 * (2 * wv + ti) + ln, 256, off);
      #pragma unroll
      for (int nt = 0; nt < 4; ++nt)
        acc2[nt][ti] = __builtin_amdgcn_mfma_f32_16x16x32_bf16(a[nt], bw2, acc2[nt][ti], 0, 0, 0);
    }
  }
  // epilogue 1 (theta) — exact conv_t repack/stream with dedicated shB
  {
    float bv[2];
    for (int ti = 0; ti < 2; ++ti) bv[ti] = ldv(b1, isbf, 16 * (2 * wv + ti) + ln);
    for (int nt = 0; nt < 4; ++nt)
      for (int ti = 0; ti < 2; ++ti)
        for (int r = 0; r < 4; ++r)
          shB[(16 * nt + q * 4 + r) * 136 + 16 * (2 * wv + ti) + ln] =
              f2bs(acc1[nt][ti][r] + bv[ti]);
    __syncthreads();
    for (int it = 0; it < 8; ++it) {
      int idx4 = it * 256 + tid;
      int n = idx4 >> 5, c4 = (idx4 & 31) * 4;
      *(ushort4*)(out1 + ((size_t)(b * 4096 + nbase + n)) * 128 + c4) =
          *(const ushort4*)&shB[n * 136 + c4];
    }
    __syncthreads();
  }
  // epilogue 2 (phi)
  {
    float bv[2];
    for (int ti = 0; ti < 2; ++ti) bv[ti] = ldv(b2, isbf, 16 * (2 * wv + ti) + ln);
    for (int nt = 0; nt < 4; ++nt)
      for (int ti = 0; ti < 2; ++ti)
        for (int r = 0; r < 4; ++r)
          shB[(16 * nt + q * 4 + r) * 136 + 16 * (2 * wv + ti) + ln] =
              f2bs(acc2[nt][ti][r] + bv[ti]);
    __syncthreads();
    for (int it = 0; it < 8; ++it) {
      int idx4 = it * 256 + tid;
      int n = idx4 >> 5, c4 = (idx4 & 31) * 4;
      *(ushort4*)(out2 + ((size_t)(b * 4096 + nbase + n)) * 128 + c4) =
          *(const ushort4*)&shB[n * 136 + c4];
    }
  }
}

// ---------------------------------------------------------------------------
// conv_n: out[b][CO][n] — EXACT round-3 version (validated).
// ---------------------------------------------------------------------------
template<int CO, int K>
__global__ __launch_bounds__(256) void conv_n_k(
    const short* __restrict__ inp, const void* __restrict__ w,
    const void* __restrict__ bias, short* __restrict__ out,
    const int* __restrict__ flag)
{
  const int isbf = *flag;
  constexpr int XS = 64 * (K + 8);
  constexpr int OS = CO * 68;
  __shared__ short sh[(XS > OS ? XS : OS)];
  const int b = blockIdx.y, nbase = blockIdx.x * 64, tid = threadIdx.x;
  const int ln = tid & 15, q = (tid >> 4) & 3, wv = tid >> 6;
  constexpr int TPW = CO / 64;
  constexpr int KS = (K == 256) ? 6 : 5;
  for (int it = 0; it < 64 * K / 1024; ++it) {
    int idx4 = it * 256 + tid;
    int n = idx4 >> KS, c4 = (idx4 & ((K / 4) - 1)) * 4;
    *(ushort4*)&sh[n * (K + 8) + c4] =
        *(const ushort4*)(inp + ((size_t)(b * 4096 + nbase + n)) * K + c4);
  }
  __syncthreads();
  f32x4 zero = {0.f, 0.f, 0.f, 0.f};
  f32x4 acc[TPW][4];
  for (int ti = 0; ti < TPW; ++ti) for (int nt = 0; nt < 4; ++nt) acc[ti][nt] = zero;

  for (int kk = 0; kk < K / 32; ++kk) {
    int off = kk * 32 + q * 8;
    bf16x8 bx[4];
    #pragma unroll
    for (int nt = 0; nt < 4; ++nt)
      bx[nt] = *(const bf16x8*)&sh[(16 * nt + ln) * (K + 8) + off];
    #pragma unroll
    for (int ti = 0; ti < TPW; ++ti) {
      bf16x8 aw = load_wfrag(w, isbf, 16 * (TPW * wv + ti) + ln, K, off);
      #pragma unroll
      for (int nt = 0; nt < 4; ++nt)
        acc[ti][nt] = __builtin_amdgcn_mfma_f32_16x16x32_bf16(aw, bx[nt], acc[ti][nt], 0, 0, 0);
    }
  }
  __syncthreads();
  for (int ti = 0; ti < TPW; ++ti)
    for (int r = 0; r < 4; ++r) {
      int co = 16 * (TPW * wv + ti) + q * 4 + r;
      float bb = ldv(bias, isbf, co);
      for (int nt = 0; nt < 4; ++nt)
        sh[co * 68 + 16 * nt + ln] = f2bs(acc[ti][nt][r] + bb);
    }
  __syncthreads();
  for (int it = 0; it < 64 * CO / 1024; ++it) {
    int idx4 = it * 256 + tid;
    int co = idx4 >> 4, n4 = (idx4 & 15) * 4;
    *(ushort4*)(out + ((size_t)(b * CO + co)) * 4096 + nbase + n4) =
        *(const ushort4*)&sh[co * 68 + n4];
  }
}

// ---------------------------------------------------------------------------
// pools — EXACT round-3 versions (validated).
// ---------------------------------------------------------------------------
__global__ __launch_bounds__(256) void pool_phi_kernel(
    const short* __restrict__ pc, short* __restrict__ phi)
{
  int idx = blockIdx.x * 256 + threadIdx.x;  // b*1024*128
  int ci = idx & 127, m = (idx >> 7) & 1023, b = idx >> 17;
  int mh = m >> 5, mw = m & 31;
  const short* p = pc + ((size_t)(b * 4096 + (mh * 2) * 64 + mw * 2)) * 128 + ci;
  float v = fmaxf(fmaxf(b2f(p[0]), b2f(p[128])),
                  fmaxf(b2f(p[64 * 128]), b2f(p[65 * 128])));
  phi[idx] = f2bs(v);
}

__global__ __launch_bounds__(256) void pool_g_kernel(
    const short* __restrict__ gc, short* __restrict__ g)
{
  int idx = blockIdx.x * 256 + threadIdx.x;  // (b*128+ci)*1024 + m
  int m = idx & 1023, bc = idx >> 10;
  int mh = m >> 5, mw = m & 31;
  const short* p = gc + (size_t)bc * 4096 + mh * 128 + mw * 2;
  float v = fmaxf(fmaxf(b2f(p[0]), b2f(p[1])), fmaxf(b2f(p[64]), b2f(p[65])));
  g[idx] = f2bs(v);
}

// ---------------------------------------------------------------------------
// MFMA flash attention — REVERTED to the round-7 VALIDATED version
// (48.6 us measured). The 32x32 rewrite (rounds 8-11) never beat it and
// carried ~100 MB of unexplained HBM writes; abandoned.
// ---------------------------------------------------------------------------
__global__ __launch_bounds__(256) void attn_kernel(
    const short* __restrict__ theta, const short* __restrict__ phi,
    const short* __restrict__ g, short* __restrict__ y)
{
  __shared__ short ph[64 * 136];
  __shared__ short gl[128 * 72];
  __shared__ short Pl[64 * 72];
  const int b = blockIdx.y, nbase = blockIdx.x * 64, tid = threadIdx.x;
  const int ln = tid & 15, q = (tid >> 4) & 3, wv = tid >> 6;

  // staging coordinates (match round-3 layout exactly)
  const int pm  = tid >> 5;          // ph row base (0..7), rows pm+8*it
  const int pc4 = (tid & 31) * 4;    // ph col (shorts)
  const int gci = tid >> 4;          // gl row base (0..15), rows gci+16*it
  const int gm4 = (tid & 15) * 4;    // gl col (shorts)
  const short* phb = phi + (size_t)b * 1024 * 128;
  const short* gb  = g   + (size_t)b * 128 * 1024;

  // prefetch tile 0 into registers
  ushort4 pf_p[8], pf_g[8];
  #pragma unroll
  for (int it = 0; it < 8; ++it)
    pf_p[it] = *(const ushort4*)(phb + ((size_t)(pm + 8 * it)) * 128 + pc4);
  #pragma unroll
  for (int it = 0; it < 8; ++it)
    pf_g[it] = *(const ushort4*)(gb + ((size_t)(gci + 16 * it)) * 1024 + gm4);

  // Q fragments: loop-invariant, straight from global
  bf16x8 a[4];
  #pragma unroll
  for (int kk = 0; kk < 4; ++kk)
    a[kk] = *(const bf16x8*)(theta +
        ((size_t)(b * 4096 + nbase + 16 * wv + ln)) * 128 + kk * 32 + q * 8);

  f32x4 zero = {0.f, 0.f, 0.f, 0.f};
  f32x4 yacc[8], lacc = zero;
  #pragma unroll
  for (int t = 0; t < 8; ++t) yacc[t] = zero;
  bf16x8 ones;
  #pragma unroll
  for (int j = 0; j < 8; ++j) ones[j] = 0x3F80;

  for (int mc = 0; mc < 16; ++mc) {
    // commit prefetched tile to LDS (prior iteration's reads were fenced by
    // the trailing __syncthreads)
    #pragma unroll
    for (int it = 0; it < 8; ++it)
      *(ushort4*)&ph[(pm + 8 * it) * 136 + pc4] = pf_p[it];
    #pragma unroll
    for (int it = 0; it < 8; ++it)
      *(ushort4*)&gl[(gci + 16 * it) * 72 + gm4] = pf_g[it];
    __syncthreads();

    // issue next tile's global loads; compute below hides the latency
    if (mc < 15) {
      const int nmc = mc + 1;
      #pragma unroll
      for (int it = 0; it < 8; ++it)
        pf_p[it] = *(const ushort4*)(phb +
            ((size_t)(nmc * 64 + pm + 8 * it)) * 128 + pc4);
      #pragma unroll
      for (int it = 0; it < 8; ++it)
        pf_g[it] = *(const ushort4*)(gb +
            ((size_t)(gci + 16 * it)) * 1024 + nmc * 64 + gm4);
    }

    // QK^T -> exp -> P (intra-wave LDS transpose), l-acc, PV
    #pragma unroll
    for (int t = 0; t < 4; ++t) {
      f32x4 s = zero;
      #pragma unroll
      for (int kk = 0; kk < 4; ++kk) {
        bf16x8 bp = *(const bf16x8*)&ph[(16 * t + ln) * 136 + kk * 32 + q * 8];
        s = __builtin_amdgcn_mfma_f32_16x16x32_bf16(a[kk], bp, s, 0, 0, 0);
      }
      #pragma unroll
      for (int r = 0; r < 4; ++r)
        Pl[(16 * wv + q * 4 + r) * 72 + 16 * t + ln] =
            f2bs(__expf(fminf(s[r], 80.f)));
    }
    bf16x8 ap[2];
    #pragma unroll
    for (int kk = 0; kk < 2; ++kk)
      ap[kk] = *(const bf16x8*)&Pl[(16 * wv + ln) * 72 + kk * 32 + q * 8];
    #pragma unroll
    for (int kk = 0; kk < 2; ++kk)
      lacc = __builtin_amdgcn_mfma_f32_16x16x32_bf16(ap[kk], ones, lacc, 0, 0, 0);
    #pragma unroll
    for (int t = 0; t < 8; ++t) {
      #pragma unroll
      for (int kk = 0; kk < 2; ++kk) {
        bf16x8 bg = *(const bf16x8*)&gl[(16 * t + ln) * 72 + kk * 32 + q * 8];
        yacc[t] = __builtin_amdgcn_mfma_f32_16x16x32_bf16(ap[kk], bg, yacc[t], 0, 0, 0);
      }
    }
    __syncthreads();
  }

  float li[4];
  #pragma unroll
  for (int r = 0; r < 4; ++r) li[r] = 1.0f / lacc[r];
  for (int t = 0; t < 8; ++t)
    for (int r = 0; r < 4; ++r)
      ph[(16 * wv + q * 4 + r) * 136 + 16 * t + ln] = f2bs(yacc[t][r] * li[r]);
  __syncthreads();
  for (int it = 0; it < 8; ++it) {
    int idx4 = it * 256 + tid;
    int n = idx4 >> 5, c4 = (idx4 & 31) * 4;
    *(ushort4*)(y + ((size_t)(b * 4096 + nbase + n)) * 128 + c4) =
        *(const ushort4*)&ph[n * 136 + c4];
  }
}

// ---------------------------------------------------------------------------
// conv_W + BN partial-stat atomics — EXACT round-4 version (validated).
// ---------------------------------------------------------------------------
__global__ __launch_bounds__(256, 4) void convW_k(
    const short* __restrict__ yb, const void* __restrict__ w,
    const void* __restrict__ bias, short* __restrict__ Wy,
    float* __restrict__ stats, const int* __restrict__ flag)
{
  const int isbf = *flag;
  __shared__ short sh[256 * 72];
  const int b = blockIdx.y, nbase = blockIdx.x * 64, tid = threadIdx.x;
  const int ln = tid & 15, q = (tid >> 4) & 3, wv = tid >> 6;

  for (int it = 0; it < 4; ++it) {
    int idx8 = it * 256 + tid;
    int n = idx8 >> 4, c8 = (idx8 & 15) * 8;
    *(uint4*)&sh[n * 136 + c8] =
        *(const uint4*)(yb + ((size_t)(b * 4096 + nbase + n)) * 128 + c8);
  }
  __syncthreads();
  f32x4 zero = {0.f, 0.f, 0.f, 0.f};
  f32x4 acc[4][4];
  for (int ti = 0; ti < 4; ++ti)
    for (int nt = 0; nt < 4; ++nt) acc[ti][nt] = zero;

  for (int kk = 0; kk < 4; ++kk) {
    int off = kk * 32 + q * 8;
    bf16x8 bx[4];
    #pragma unroll
    for (int nt = 0; nt < 4; ++nt)
      bx[nt] = *(const bf16x8*)&sh[(16 * nt + ln) * 136 + off];
    #pragma unroll
    for (int ti = 0; ti < 4; ++ti) {
      bf16x8 aw = load_wfrag(w, isbf, 16 * (4 * wv + ti) + ln, 128, off);
      #pragma unroll
      for (int nt = 0; nt < 4; ++nt)
        acc[ti][nt] = __builtin_amdgcn_mfma_f32_16x16x32_bf16(aw, bx[nt], acc[ti][nt], 0, 0, 0);
    }
  }
  __syncthreads();
  #pragma unroll
  for (int ti = 0; ti < 4; ++ti)
    #pragma unroll
    for (int r = 0; r < 4; ++r) {
      int co = 16 * (4 * wv + ti) + 4 * q + r;
      float bb = ldv(bias, isbf, co);
      #pragma unroll
      for (int nt = 0; nt < 4; ++nt)
        sh[co * 72 + 16 * nt + ln] = f2bs(acc[ti][nt][r] + bb);
    }
  __syncthreads();
  {
    int co = tid;
    float s = 0.f, s2 = 0.f;
    for (int i = 0; i < 64; ++i) {
      float v = b2f((unsigned short)sh[co * 72 + i]);
      s += v; s2 += v * v;
    }
    atomicAdd(&stats[co], s);
    atomicAdd(&stats[256 + co], s2);
  }
  for (int it = 0; it < 8; ++it) {
    int idx8 = it * 256 + tid;
    int co = idx8 >> 3, n8 = (idx8 & 7) * 8;
    *(uint4*)(Wy + ((size_t)(b * 256 + co)) * 4096 + nbase + n8) =
        *(const uint4*)&sh[co * 72 + n8];
  }
}

// ---------------------------------------------------------------------------
// BN apply + residual, x4 — EXACT round-4/6 version (validated).
// ---------------------------------------------------------------------------
__global__ __launch_bounds__(256) void bn_apply4(
    const short* __restrict__ Wy, const void* __restrict__ x,
    const float* __restrict__ stats, const void* __restrict__ gamma,
    const void* __restrict__ beta, void* __restrict__ out,
    const int* __restrict__ flag)
{
  const int isbf = *flag;
  int t = blockIdx.x * 256 + threadIdx.x;
  int idx4 = t * 4;
  int c = (idx4 >> 12) & 255;
  float s = stats[c], s2 = stats[256 + c];
  float mean = s * (1.0f / 32768.0f);
  float var = fmaxf(s2 * (1.0f / 32768.0f) - mean * mean, 0.f);
  float scale = rsqrtf(var + 1e-5f) * ldv(gamma, isbf, c);
  float shift = ldv(beta, isbf, c) - mean * scale;
  ushort4 wy = *(const ushort4*)(Wy + idx4);
  float xv[4];
  if (isbf) {
    ushort4 xu = *(const ushort4*)((const unsigned short*)x + idx4);
    xv[0] = b2f(xu.x); xv[1] = b2f(xu.y); xv[2] = b2f(xu.z); xv[3] = b2f(xu.w);
  } else {
    float4 xf = *(const float4*)((const float*)x + idx4);
    xv[0] = xf.x; xv[1] = xf.y; xv[2] = xf.z; xv[3] = xf.w;
  }
  float v0 = b2f(wy.x) * scale + shift + xv[0];
  float v1 = b2f(wy.y) * scale + shift + xv[1];
  float v2 = b2f(wy.z) * scale + shift + xv[2];
  float v3 = b2f(wy.w) * scale + shift + xv[3];
  if (isbf) {
    uint2 o; o.x = pk2(v0, v1); o.y = pk2(v2, v3);
    *(uint2*)((unsigned short*)out + idx4) = o;
  } else {
    float4 o = make_float4(v0, v1, v2, v3);
    *(float4*)((float*)out + idx4) = o;
  }
}

// ---------------------------------------------------------------------------
extern "C" void kernel_launch(void* const* d_in, const int* in_sizes, int n_in,
                              void* d_out, int out_size, void* d_ws, size_t ws_size,
                              hipStream_t stream) {
  const void* x       = d_in[0];
  const void* theta_w = d_in[1];
  const void* theta_b = d_in[2];
  const void* phi_w   = d_in[3];
  const void* phi_b   = d_in[4];
  const void* g_w     = d_in[5];
  const void* g_b     = d_in[6];
  const void* W_w     = d_in[7];
  const void* W_b     = d_in[8];
  const void* gamma   = d_in[9];
  const void* beta    = d_in[10];

  char* wsb = (char*)d_ws;
  // round-3 layout exactly:
  //   [0, 16.78M)      xT -> ybuf
  //   [16.78M, 25.17M) theta -> W_y first half
  //   [25.17M, 33.55M) scratch (phi_c then g_c) -> W_y second half
  //   [33.55M, 35.65M) phi   [b][m][ci]
  //   [35.65M, 37.75M) gg    [b][ci][m]
  //   [37.75M+)        stats (512 f32), flag
  short* xT      = (short*)(wsb + 0);
  short* ybuf    = (short*)(wsb + 0);
  short* theta   = (short*)(wsb + 16777216);
  short* W_y     = (short*)(wsb + 16777216);
  short* scratch = (short*)(wsb + 25165824);
  short* phi     = (short*)(wsb + 33554432);
  short* gg      = (short*)(wsb + 35651584);
  float* stats   = (float*)(wsb + 37748736);
  int*   flag    = (int*)  (wsb + 37750784);

  dim3 blk(256);
  dim3 cgrid(64, 8);
  dim3 tgrid(64, 4, 8);

  hipMemsetAsync(stats, 0, 2048, stream);
  sniff_kernel<<<1, blk, 0, stream>>>((const unsigned short*)x, flag);
  transpose_x<<<tgrid, blk, 0, stream>>>(x, xT, flag);
  conv_tp_k<<<cgrid, blk, 0, stream>>>(xT, theta_w, theta_b, theta,
                                       phi_w, phi_b, scratch, flag);
  pool_phi_kernel<<<4096, blk, 0, stream>>>(scratch, phi);
  conv_n_k<128, 256><<<cgrid, blk, 0, stream>>>(xT, g_w, g_b, scratch, flag);
  pool_g_kernel<<<4096, blk, 0, stream>>>(scratch, gg);
  attn_kernel<<<cgrid, blk, 0, stream>>>(theta, phi, gg, ybuf);
  convW_k<<<cgrid, blk, 0, stream>>>(ybuf, W_w, W_b, W_y, stats, flag);
  bn_apply4<<<8192, blk, 0, stream>>>(W_y, x, stats, gamma, beta, d_out, flag);
}